// Round 1
// baseline (3411.114 us; speedup 1.0000x reference)
//
#include <hip/hip_runtime.h>
#include <hip/hip_bf16.h>
#include <math.h>

// ---------------------------------------------------------------------------
// GAT 2-layer network on MI355X.
// Strategy: build CSR (edges grouped by dst) once per launch, then for each
// of T=8 time steps run: GEMM1(+att dots) -> edge-softmax-aggregate(+ELU)
// -> GEMM2(+att dots) -> edge-softmax-aggregate(+log_softmax).
// Edge aggregation uses flash-style online softmax: one wave per dst node,
// lane = head*C + channel, no float atomics.
// ---------------------------------------------------------------------------

#define WAVE 64

// ---- CSR construction ------------------------------------------------------

__global__ __launch_bounds__(256) void init_cnt_kernel(int* cnt, int N) {
    int i = blockIdx.x * 256 + threadIdx.x;
    if (i < N) cnt[i] = 1;  // self-loop contributes 1 to every node
}

__global__ __launch_bounds__(256) void count_edges_kernel(const int* __restrict__ dsts,
                                                          int* cnt, int E) {
    int i = blockIdx.x * 256 + threadIdx.x;
    if (i < E) atomicAdd(&cnt[dsts[i]], 1);
}

__global__ __launch_bounds__(1024) void scan_kernel(const int* __restrict__ cnt,
                                                    int* row, int* cur, int N) {
    __shared__ int ls[1024];
    int t = threadIdx.x;
    int chunk = (N + 1023) / 1024;
    int b = t * chunk;
    int sum = 0;
    for (int i = 0; i < chunk; ++i) {
        int idx = b + i;
        if (idx < N) sum += cnt[idx];
    }
    ls[t] = sum;
    __syncthreads();
    // Hillis-Steele inclusive scan
    for (int off = 1; off < 1024; off <<= 1) {
        int v = (t >= off) ? ls[t - off] : 0;
        __syncthreads();
        ls[t] += v;
        __syncthreads();
    }
    int run = (t == 0) ? 0 : ls[t - 1];
    for (int i = 0; i < chunk; ++i) {
        int idx = b + i;
        if (idx < N) {
            int c = cnt[idx];
            row[idx] = run;
            cur[idx] = run;
            run += c;
        }
    }
    if (t == 1023) row[N] = ls[1023];
}

__global__ __launch_bounds__(256) void fill_csr_kernel(const int* __restrict__ srcs,
                                                       const int* __restrict__ dsts,
                                                       int* cur, int* esrc, int E, int N) {
    int i = blockIdx.x * 256 + threadIdx.x;
    if (i >= E + N) return;
    int s, d;
    if (i < E) { s = srcs[i]; d = dsts[i]; }
    else       { s = i - E;   d = s; }      // self-loops appended
    int pos = atomicAdd(&cur[d], 1);
    esrc[pos] = s;
}

// ---- GEMM (h = x@W) fused with attention dot-products ----------------------
// H*C == 64. att flat layout [H,C] matches lane index c = head*C + cc.

template <int H, int C>
__global__ __launch_bounds__(256) void gemm_att_kernel(
    const float* __restrict__ xin,   // [N,64]
    const float* __restrict__ Wm,    // [64,64]  (h[n,c] = sum_k x[n,k]*W[k,c])
    const float* __restrict__ att_s, // [H*C]
    const float* __restrict__ att_d, // [H*C]
    float* __restrict__ hout,        // [N,64]
    float* __restrict__ asrc,        // [N*H]
    float* __restrict__ adst,        // [N*H]
    int N) {
    __shared__ float Ws[64 * 64];
    int tid = threadIdx.x;
    for (int i = tid; i < 64 * 64; i += 256) Ws[i] = Wm[i];
    __syncthreads();

    int c  = tid & 63;
    int wv = tid >> 6;  // wave id within block: 0..3
    int base = blockIdx.x * 32;
    float as_w = att_s[c];
    float ad_w = att_d[c];

    for (int it = 0; it < 8; ++it) {
        int n = base + it * 4 + wv;
        if (n >= N) return;
        const float* xr = xin + (size_t)n * 64;
        float acc = 0.f;
#pragma unroll
        for (int k = 0; k < 64; ++k) acc = fmaf(xr[k], Ws[k * 64 + c], acc);
        hout[(size_t)n * 64 + c] = acc;

        float vs = acc * as_w;
        float vd = acc * ad_w;
#pragma unroll
        for (int off = 1; off < C; off <<= 1) {
            vs += __shfl_xor(vs, off, 64);
            vd += __shfl_xor(vd, off, 64);
        }
        if ((c % C) == 0) {
            int hd = c / C;
            asrc[(size_t)n * H + hd] = vs;
            adst[(size_t)n * H + hd] = vd;
        }
    }
}

// ---- Edge-softmax aggregation (one wave per dst node) ----------------------

template <int H, int C, bool FINAL>
__global__ __launch_bounds__(256) void gat_edge_kernel(
    const float* __restrict__ h,     // [N,64]
    const float* __restrict__ asrc,  // [N*H]
    const float* __restrict__ adst,  // [N*H]
    const int* __restrict__ row,     // [N+1]
    const int* __restrict__ esrc,    // [Etot]
    const float* __restrict__ bias,  // [64]
    float* __restrict__ out,         // [N,64] (y1 or d_out slice)
    int N) {
    int tid  = threadIdx.x;
    int lane = tid & 63;
    int n    = blockIdx.x * 4 + (tid >> 6);
    if (n >= N) return;

    int hd = lane / C;
    float adn = adst[(size_t)n * H + hd];
    int e0 = row[n], e1 = row[n + 1];

    float m = -INFINITY, lsum = 0.f, acc = 0.f;
    for (int e = e0; e < e1; ++e) {
        int s = esrc[e];
        float al = asrc[(size_t)s * H + hd] + adn;
        al = al > 0.f ? al : 0.2f * al;          // leaky_relu(0.2)
        float mn    = fmaxf(m, al);
        float scale = __expf(m - mn);            // exp(-inf)=0 on first iter
        float p     = __expf(al - mn);
        float hv    = h[(size_t)s * 64 + lane];
        lsum = lsum * scale + p;
        acc  = acc * scale + p * hv;
        m = mn;
    }

    float v = acc / (lsum + 1e-16f) + bias[lane];
    if (!FINAL) {
        // ELU
        out[(size_t)n * 64 + lane] = v > 0.f ? v : expm1f(v);
    } else {
        // log_softmax over 64 features (one wave)
        float mx = v;
#pragma unroll
        for (int off = 1; off < 64; off <<= 1) mx = fmaxf(mx, __shfl_xor(mx, off, 64));
        float ex = __expf(v - mx);
        float sm = ex;
#pragma unroll
        for (int off = 1; off < 64; off <<= 1) sm += __shfl_xor(sm, off, 64);
        out[(size_t)n * 64 + lane] = (v - mx) - __logf(sm);
    }
}

// ---------------------------------------------------------------------------

extern "C" void kernel_launch(void* const* d_in, const int* in_sizes, int n_in,
                              void* d_out, int out_size, void* d_ws, size_t ws_size,
                              hipStream_t stream) {
    const float* x        = (const float*)d_in[0];   // [T,N,64]
    const int*   eidx     = (const int*)d_in[1];     // [2,E]
    const float* W1       = (const float*)d_in[2];   // [64,64]
    const float* att_src1 = (const float*)d_in[3];   // [8,8]
    const float* att_dst1 = (const float*)d_in[4];   // [8,8]
    const float* bias1    = (const float*)d_in[5];   // [64]
    const float* W2       = (const float*)d_in[6];   // [64,64]
    const float* att_src2 = (const float*)d_in[7];   // [1,64]
    const float* att_dst2 = (const float*)d_in[8];   // [1,64]
    const float* bias2    = (const float*)d_in[9];   // [64]
    float* dout = (float*)d_out;

    const int N = 50000;
    const int F = 64;
    const int E = in_sizes[1] / 2;
    const int T = in_sizes[0] / (N * F);
    const int Etot = E + N;

    const int* srcs = eidx;
    const int* dsts = eidx + E;

    // workspace carve-up (256B aligned)
    char* ws = (char*)d_ws;
    size_t off = 0;
    auto carve = [&](size_t bytes) -> void* {
        void* p = ws + off;
        off = (off + bytes + 255) & ~(size_t)255;
        return p;
    };
    float* h_buf = (float*)carve((size_t)N * 64 * sizeof(float));
    float* y1    = (float*)carve((size_t)N * 64 * sizeof(float));
    float* asrc  = (float*)carve((size_t)N * 8 * sizeof(float));
    float* adst  = (float*)carve((size_t)N * 8 * sizeof(float));
    int*   rowp  = (int*)carve((size_t)(N + 1) * sizeof(int));
    int*   cnt   = (int*)carve((size_t)N * sizeof(int));
    int*   cur   = (int*)carve((size_t)N * sizeof(int));
    int*   esrc  = (int*)carve((size_t)Etot * sizeof(int));
    (void)ws_size;

    // --- build CSR (by dst) ---
    init_cnt_kernel<<<(N + 255) / 256, 256, 0, stream>>>(cnt, N);
    count_edges_kernel<<<(E + 255) / 256, 256, 0, stream>>>(dsts, cnt, E);
    scan_kernel<<<1, 1024, 0, stream>>>(cnt, rowp, cur, N);
    fill_csr_kernel<<<(E + N + 255) / 256, 256, 0, stream>>>(srcs, dsts, cur, esrc, E, N);

    // --- per-timestep pipeline ---
    int gemm_grid = (N + 31) / 32;
    int edge_grid = (N + 3) / 4;
    for (int t = 0; t < T; ++t) {
        const float* xt = x + (size_t)t * N * F;
        float* ot = dout + (size_t)t * N * F;

        gemm_att_kernel<8, 8><<<gemm_grid, 256, 0, stream>>>(
            xt, W1, att_src1, att_dst1, h_buf, asrc, adst, N);
        gat_edge_kernel<8, 8, false><<<edge_grid, 256, 0, stream>>>(
            h_buf, asrc, adst, rowp, esrc, bias1, y1, N);
        gemm_att_kernel<1, 64><<<gemm_grid, 256, 0, stream>>>(
            y1, W2, att_src2, att_dst2, h_buf, asrc, adst, N);
        gat_edge_kernel<1, 64, true><<<edge_grid, 256, 0, stream>>>(
            h_buf, asrc, adst, rowp, esrc, bias2, ot, N);
    }
}